// Round 8
// baseline (266.485 us; speedup 1.0000x reference)
//
#include <hip/hip_runtime.h>
#include <stdint.h>

// IDCT (DCT-III, DREAMPlace scaling) via even/odd split, fully fused:
//   E[m][p] = sum_{n even} x[m][n]*c(n,p),  O[m][p] = sum_{n odd} ...,
//   out[p] = E+O, out[N-1-p] = E-O   (c(n,N-1-p) = (-1)^n c(n,p)).
// R13 (R8/R9/R10/R12: four schedules, 72-76us, MfmaUtil 39%, no pipe
// saturated -> the shared 2-barrier/BK=32 lockstep + ratio-2.0 wave tiles
// are the invariant; attack structure, not schedule):
//  (1) Block 256m x 128p, 512 thr, 8 BRANCH-SPLIT waves: wave = 128m x 64p
//      of ONE branch (E or O) = 8x4 frags, 32 MFMAs per 12 ds_reads
//      (ratio 2.67 vs 2.0) -> LDS reads/CU-iter 128->96 KB, MFMA-per-
//      barrier 2x.
//  (2) TRIPLE-buffered LDS (3 x 48 KB = 144 KB of the 160 KB/CU) -> ONE
//      barrier per iter (barrier(t) alone proves stage(t+2)'s buffer free);
//      counted vmcnt(6) depth-2 prefetch kept. Barriers 128 -> 64.
//  (3) Butterfly via one-time epilogue LDS exchange: E-wave dumps rows
//      64-127 of its acc, O-wave dumps rows 0-63, partner reads, both
//      write lo/hi halves. Accumulation order bit-identical to R10.
// ws: Ae_t 16MB | Ao_t 16MB | Ce_t 8MB | Co_t 8MB = 48MB.
// Tile layout: plane[(tile = bt*64 + kb)*4096 + g*1024 + r*8 + j]
//   = elem(row=r, k=kb*32+g*8+j) of the (bt,kb) 128x32 tile.

#define Md 4096
#define Nfull 4096
#define Ph 2048   // half output width
#define Kh 2048   // half reduction
#define BM 256
#define BN 128
#define BK 32
#define NKB 64    // Kh/BK k-blocks

typedef short bf16x8 __attribute__((ext_vector_type(8)));
typedef float floatx4 __attribute__((ext_vector_type(4)));
typedef unsigned short ushort_t;

__device__ __forceinline__ ushort_t f2bf(float f) {
  union { float f; uint32_t u; } v; v.f = f;
  uint32_t u = v.u;
  return (ushort_t)((u + 0x7fffu + ((u >> 16) & 1u)) >> 16);
}

// blocks [0,2048): deinterleave x into tiled Ae/Ao. Block=(bm,kb) tile pair;
//   thread t: row r=t>>1, half h=t&1 -> reads 32 consecutive floats (128B),
//   writes 2 int4 per plane at tiled offsets.
// blocks [2048,4096): cosine tables straight into tiled layout, 2 chunks/thr.
__global__ __launch_bounds__(256) void prep_kernel(const float* __restrict__ x,
                                                   ushort_t* __restrict__ Ae,
                                                   ushort_t* __restrict__ Ao,
                                                   ushort_t* __restrict__ Ce,
                                                   ushort_t* __restrict__ Co) {
  int b = blockIdx.x;
  int t = threadIdx.x;
  if (b < 2048) {
    int bm = b >> 6, kb = b & 63;
    int r = t >> 1, h = t & 1;
    const float4* xp = (const float4*)(x + (((size_t)(bm * 128 + r)) << 12) + kb * 64 + h * 32);
    float4 v0 = xp[0], v1 = xp[1], v2 = xp[2], v3 = xp[3];
    float4 v4 = xp[4], v5 = xp[5], v6 = xp[6], v7 = xp[7];
    union { ushort_t us[8]; int4 v; } e0, e1, o0, o1;
    e0.us[0] = f2bf(v0.x); o0.us[0] = f2bf(v0.y);
    e0.us[1] = f2bf(v0.z); o0.us[1] = f2bf(v0.w);
    e0.us[2] = f2bf(v1.x); o0.us[2] = f2bf(v1.y);
    e0.us[3] = f2bf(v1.z); o0.us[3] = f2bf(v1.w);
    e0.us[4] = f2bf(v2.x); o0.us[4] = f2bf(v2.y);
    e0.us[5] = f2bf(v2.z); o0.us[5] = f2bf(v2.w);
    e0.us[6] = f2bf(v3.x); o0.us[6] = f2bf(v3.y);
    e0.us[7] = f2bf(v3.z); o0.us[7] = f2bf(v3.w);
    e1.us[0] = f2bf(v4.x); o1.us[0] = f2bf(v4.y);
    e1.us[1] = f2bf(v4.z); o1.us[1] = f2bf(v4.w);
    e1.us[2] = f2bf(v5.x); o1.us[2] = f2bf(v5.y);
    e1.us[3] = f2bf(v5.z); o1.us[3] = f2bf(v5.w);
    e1.us[4] = f2bf(v6.x); o1.us[4] = f2bf(v6.y);
    e1.us[5] = f2bf(v6.z); o1.us[5] = f2bf(v6.w);
    e1.us[6] = f2bf(v7.x); o1.us[6] = f2bf(v7.y);
    e1.us[7] = f2bf(v7.z); o1.us[7] = f2bf(v7.w);
    size_t tb = ((size_t)(bm * 64 + kb)) << 12;      // tile base (elems)
    int c0 = (2 * h) * 1024 + r * 8;                 // g = 2h
    int c1 = c0 + 1024;                              // g = 2h+1
    *(int4*)(Ae + tb + c0) = e0.v;
    *(int4*)(Ae + tb + c1) = e1.v;
    *(int4*)(Ao + tb + c0) = o0.v;
    *(int4*)(Ao + tb + c1) = o1.v;
  } else {
    int b2 = b - 2048;
    int plane = b2 >> 10;            // 0 = Ce (even n), 1 = Co (odd n)
    int bn = (b2 & 1023) >> 6, kb = b2 & 63;
    ushort_t* T = plane ? Co : Ce;
    size_t tb = ((size_t)(bn * 64 + kb)) << 12;
    const float s = 3.14159265358979f / 8192.0f;     // pi/(2N)
#pragma unroll
    for (int half = 0; half < 2; ++half) {
      int cc = t + half * 256;       // chunk index within tile [0,512)
      int g = cc >> 7, r = cc & 127;
      int p = bn * 128 + r;
      int tp = 2 * p + 1;
      int ni = kb * 32 + g * 8;
      union { ushort_t us[8]; int4 v; } pk;
#pragma unroll
      for (int jj = 0; jj < 8; ++jj) {
        int n = 2 * (ni + jj) + plane;
        int ang = (n * tp) & 16383;  // mod 4N: exact int reduction
        float c = (n == 0) ? 1.0f : 2.0f * __cosf(s * (float)ang);
        pk.us[jj] = f2bf(c);
      }
      *(int4*)(T + tb + cc * 8) = pk.v;
    }
  }
}

// Fused dual GEMM + butterfly. Block 256m x 128p, BK=32, 512 threads.
// 8 waves: wid = br + ch*2 + rh*4 -> wave = rows [rh*128,+128) x cols
// [ch*64,+64) of branch br (E/O). Frags 8x4, acc 128 regs, 12 ds_read +
// 32 MFMA per iter (ratio 2.67).
// LDS buffer (24576 elems = 48 KB): [AE t0|AE t1|AO t0|AO t1|BE|BO] at
// elem offsets 0,4096,8192,12288,16384,20480. Three static buffers T0/T1/T2
// (NoAlias provable); ONE s_barrier per iter; counted vmcnt(6), never 0
// in the main loop (STAGE = 6 GLDS/wave, depth-2 in flight).
__global__ __launch_bounds__(512, 1) void gemm_fused(const ushort_t* __restrict__ Ae,
                                                     const ushort_t* __restrict__ Ao,
                                                     const ushort_t* __restrict__ Ce,
                                                     const ushort_t* __restrict__ Co,
                                                     float* __restrict__ out) {
  __shared__ __align__(16) ushort_t T0[24576];   // 48 KB
  __shared__ __align__(16) ushort_t T1[24576];   // 48 KB
  __shared__ __align__(16) ushort_t T2[24576];   // 48 KB -> 144 KB total

  const int tid = threadIdx.x;
  const int wid = tid >> 6;
  const int lane = tid & 63;

  const int br = wid & 1;          // 0 = E, 1 = O
  const int ch = (wid >> 1) & 1;   // col half
  const int rh = wid >> 2;         // row half
  const int lrow = lane & 15;
  const int lq = lane >> 4;
  const int g1024 = lq << 10;
  const int rb8 = lrow << 3;
  const int abase = br * 8192 + rh * 4096;
  const int bbase = 16384 + br * 4096 + ch * 512;

  const int bm = blockIdx.y;   // m-tile index (256 rows)
  const int bn = blockIdx.x;   // p-tile index (128 cols)

  floatx4 acc[8][4] = {};

  // Staging source pointers (per thread, 16B chunk tid of each 8KB plane).
  const ushort_t* pA0 = Ae + (((size_t)(128 * bm)) << 12) + (tid << 3);
  const ushort_t* pA1 = pA0 + ((size_t)64 << 12);
  const ushort_t* pO0 = Ao + (((size_t)(128 * bm)) << 12) + (tid << 3);
  const ushort_t* pO1 = pO0 + ((size_t)64 << 12);
  const ushort_t* pBe = Ce + (((size_t)(64 * bn)) << 12) + (tid << 3);
  const ushort_t* pBo = Co + (((size_t)(64 * bn)) << 12) + (tid << 3);

#define GLDS(src, dst) __builtin_amdgcn_global_load_lds( \
      (const __attribute__((address_space(1))) void*)(src), \
      (__attribute__((address_space(3))) void*)(dst), 16, 0, 0)

#define STAGE(SB, tt) do { \
    size_t so_ = ((size_t)(tt)) << 12; \
    GLDS(pA0 + so_, SB + (tid << 3)); \
    GLDS(pA1 + so_, SB + 4096 + (tid << 3)); \
    GLDS(pO0 + so_, SB + 8192 + (tid << 3)); \
    GLDS(pO1 + so_, SB + 12288 + (tid << 3)); \
    GLDS(pBe + so_, SB + 16384 + (tid << 3)); \
    GLDS(pBo + so_, SB + 20480 + (tid << 3)); \
  } while (0)

#define COMPUTE(SB) do { \
    bf16x8 b_[4]; \
    _Pragma("unroll") \
    for (int jn_ = 0; jn_ < 4; ++jn_) \
      b_[jn_] = *(const bf16x8*)(SB + bbase + g1024 + rb8 + jn_ * 128); \
    __builtin_amdgcn_s_setprio(1); \
    _Pragma("unroll") \
    for (int im_ = 0; im_ < 8; ++im_) { \
      bf16x8 a_ = *(const bf16x8*)(SB + abase + g1024 + rb8 + im_ * 128); \
      _Pragma("unroll") \
      for (int jn_ = 0; jn_ < 4; ++jn_) \
        acc[im_][jn_] = __builtin_amdgcn_mfma_f32_16x16x32_bf16(a_, b_[jn_], acc[im_][jn_], 0, 0, 0); \
    } \
    __builtin_amdgcn_s_setprio(0); \
  } while (0)

#define WAITVM(n) do { \
    asm volatile("s_waitcnt vmcnt(" #n ")" ::: "memory"); \
    __builtin_amdgcn_sched_barrier(0); \
  } while (0)

  // Prologue: stage tiles 0 and 1 (12 GLDS in flight).
  STAGE(T0, 0);
  STAGE(T1, 1);

  for (int tt = 0; tt < 60; tt += 3) {
    WAITVM(6);                            // tile tt landed; tt+1 in flight
    __builtin_amdgcn_s_barrier();
    COMPUTE(T0);
    STAGE(T2, tt + 2);
    WAITVM(6);
    __builtin_amdgcn_s_barrier();
    COMPUTE(T1);
    STAGE(T0, tt + 3);
    WAITVM(6);
    __builtin_amdgcn_s_barrier();
    COMPUTE(T2);
    STAGE(T1, tt + 4);
  }
  // t = 60..63 tail (tiles 60,61 staged; 62,63 staged below).
  WAITVM(6);
  __builtin_amdgcn_s_barrier();
  COMPUTE(T0);                            // t=60 (60%3=0)
  STAGE(T2, 62);
  WAITVM(6);
  __builtin_amdgcn_s_barrier();
  COMPUTE(T1);                            // t=61
  STAGE(T0, 63);
  WAITVM(6);
  __builtin_amdgcn_s_barrier();
  COMPUTE(T2);                            // t=62 (63 still in flight)
  WAITVM(0);
  __builtin_amdgcn_s_barrier();
  COMPUTE(T0);                            // t=63

#undef GLDS
#undef STAGE
#undef COMPUTE
#undef WAITVM

  // ---- Epilogue: cross-wave butterfly via LDS exchange. ----
  __syncthreads();   // all MFMA reads done; LDS reusable
  float* my = (wid < 3) ? ((float*)T0 + wid * 4096)
            : (wid < 6) ? ((float*)T1 + (wid - 3) * 4096)
                        : ((float*)T2 + (wid - 6) * 4096);
  const int pw = wid ^ 1;   // partner: same rh, ch; other branch
  const float* pr = (pw < 3) ? ((const float*)T0 + pw * 4096)
                  : (pw < 6) ? ((const float*)T1 + (pw - 3) * 4096)
                             : ((const float*)T2 + (pw - 6) * 4096);
  {
    // E dumps im 4..7 (rows rh*128+64..127); O dumps im 0..3.
    const int dbase = (br ^ 1) << 2;
#pragma unroll
    for (int i4 = 0; i4 < 4; ++i4)
#pragma unroll
      for (int jn = 0; jn < 4; ++jn)
        *(floatx4*)(my + (i4 * 4 + jn) * 256 + lane * 4) = acc[dbase + i4][jn];
  }
  __syncthreads();
  // E keeps im 0..3 (+ partner O's dump of same rows); O keeps im 4..7.
  const int kbase = br << 2;
#pragma unroll
  for (int i4 = 0; i4 < 4; ++i4) {
    int im = kbase + i4;
    int rb = bm * BM + rh * 128 + im * 16 + lq * 4;
#pragma unroll
    for (int jn = 0; jn < 4; ++jn) {
      floatx4 oth = *(const floatx4*)(pr + (i4 * 4 + jn) * 256 + lane * 4);
      int p = bn * BN + ch * 64 + jn * 16 + lrow;
      float* lo = out + (size_t)rb * Nfull + p;
      float* hi = out + (size_t)rb * Nfull + (Nfull - 1 - p);
#pragma unroll
      for (int r = 0; r < 4; ++r) {
        float e = br ? oth[r] : acc[im][jn][r];
        float o = br ? acc[im][jn][r] : oth[r];
        lo[(size_t)r * Nfull] = e + o;
        hi[(size_t)r * Nfull] = e - o;
      }
    }
  }
}

extern "C" void kernel_launch(void* const* d_in, const int* in_sizes, int n_in,
                              void* d_out, int out_size, void* d_ws, size_t ws_size,
                              hipStream_t stream) {
  const float* x = (const float*)d_in[0];
  float* out = (float*)d_out;
  ushort_t* Ae = (ushort_t*)d_ws;                      // 16 MB (tiled)
  ushort_t* Ao = Ae + (size_t)8 * 1024 * 1024;         // 16 MB
  ushort_t* Ce = Ao + (size_t)8 * 1024 * 1024;         // 8 MB
  ushort_t* Co = Ce + (size_t)4 * 1024 * 1024;         // 8 MB

  prep_kernel<<<4096, 256, 0, stream>>>(x, Ae, Ao, Ce, Co);

  dim3 grid(Ph / BN, Md / BM);  // 16 x 16 = 256 blocks = 1/CU
  gemm_fused<<<grid, 512, 0, stream>>>(Ae, Ao, Ce, Co, out);
}

// Round 9
// 183.325 us; speedup vs baseline: 1.4536x; 1.4536x over previous
//
#include <hip/hip_runtime.h>
#include <stdint.h>

// IDCT (DCT-III, DREAMPlace scaling) via even/odd split, fully fused:
//   E[m][p] = sum_{n even} x[m][n]*c(n,p),  O[m][p] = sum_{n odd} ...,
//   out[p] = E+O, out[N-1-p] = E-O   (c(n,N-1-p) = (-1)^n c(n,p)).
// R14 (post-mortem R13: 256m-tile spilled — 128-float acc + 6 staging ptrs
// + triple-buffer addressing > 256 unified regs/wave at 8 waves/wg ->
// 414MB scratch traffic. Reverted to the best-measured base (R9: 71.5us
// gemm, 176.5 total) and applied three bounded levers):
//  (1) MFMA shape 16x16x32 -> 32x32x16: measured ceiling 2382 vs 2075 TF
//      (+15%), instruction count halves (16 vs 32 MFMA/iter), same ds_read
//      bytes (pre-tiled layout serves both shapes: lanes 0-31 read 512B
//      contiguous, conflict-free). C/D map col=lane&31,
//      row=(r&3)+8*(r>>2)+4*(lane>>5) [m74/m101-verified]. Epilogue stores
//      become 2x128B segments per instruction.
//  (2) T1 XCD-bijective swizzle (512 blocks % 8 == 0): each XCD owns 4
//      contiguous bm rows -> A-tile (1MB) reused 16x inside one L2.
//  (3) Chebyshev cosine recurrence in prep_tab: 3 __cosf + 6 FMA per
//      8 entries (c_j = 2cos(step)*c_{j-1} - c_{j-2}).
// ws: Ae_t 16MB | Ao_t 16MB | Ce_t 8MB | Co_t 8MB = 48MB.
// Tile layout: plane[(tile = bt*64 + kb)*4096 + g*1024 + r*8 + j]
//   = elem(row=r, k=kb*32+g*8+j) of the (bt,kb) 128x32 tile.

#define Md 4096
#define Nfull 4096
#define Ph 2048   // half output width
#define Kh 2048   // half reduction
#define BM 128
#define BN 128
#define BK 32
#define NKB 64    // Kh/BK k-blocks

typedef short bf16x8 __attribute__((ext_vector_type(8)));
typedef float floatx16 __attribute__((ext_vector_type(16)));
typedef unsigned short ushort_t;

__device__ __forceinline__ ushort_t f2bf(float f) {
  union { float f; uint32_t u; } v; v.f = f;
  uint32_t u = v.u;
  return (ushort_t)((u + 0x7fffu + ((u >> 16) & 1u)) >> 16);
}

// blocks [0,2048): deinterleave x into tiled Ae/Ao. Block=(bm,kb) tile pair;
//   thread t: row r=t>>1, half h=t&1 -> reads 32 consecutive floats (128B),
//   writes 2 int4 per plane at tiled offsets.
// blocks [2048,4096): cosine tables straight into tiled layout, 2 chunks/thr,
//   Chebyshev recurrence (3 transcendentals per 8 entries).
__global__ __launch_bounds__(256) void prep_kernel(const float* __restrict__ x,
                                                   ushort_t* __restrict__ Ae,
                                                   ushort_t* __restrict__ Ao,
                                                   ushort_t* __restrict__ Ce,
                                                   ushort_t* __restrict__ Co) {
  int b = blockIdx.x;
  int t = threadIdx.x;
  if (b < 2048) {
    int bm = b >> 6, kb = b & 63;
    int r = t >> 1, h = t & 1;
    const float4* xp = (const float4*)(x + (((size_t)(bm * 128 + r)) << 12) + kb * 64 + h * 32);
    float4 v0 = xp[0], v1 = xp[1], v2 = xp[2], v3 = xp[3];
    float4 v4 = xp[4], v5 = xp[5], v6 = xp[6], v7 = xp[7];
    union { ushort_t us[8]; int4 v; } e0, e1, o0, o1;
    e0.us[0] = f2bf(v0.x); o0.us[0] = f2bf(v0.y);
    e0.us[1] = f2bf(v0.z); o0.us[1] = f2bf(v0.w);
    e0.us[2] = f2bf(v1.x); o0.us[2] = f2bf(v1.y);
    e0.us[3] = f2bf(v1.z); o0.us[3] = f2bf(v1.w);
    e0.us[4] = f2bf(v2.x); o0.us[4] = f2bf(v2.y);
    e0.us[5] = f2bf(v2.z); o0.us[5] = f2bf(v2.w);
    e0.us[6] = f2bf(v3.x); o0.us[6] = f2bf(v3.y);
    e0.us[7] = f2bf(v3.z); o0.us[7] = f2bf(v3.w);
    e1.us[0] = f2bf(v4.x); o1.us[0] = f2bf(v4.y);
    e1.us[1] = f2bf(v4.z); o1.us[1] = f2bf(v4.w);
    e1.us[2] = f2bf(v5.x); o1.us[2] = f2bf(v5.y);
    e1.us[3] = f2bf(v5.z); o1.us[3] = f2bf(v5.w);
    e1.us[4] = f2bf(v6.x); o1.us[4] = f2bf(v6.y);
    e1.us[5] = f2bf(v6.z); o1.us[5] = f2bf(v6.w);
    e1.us[6] = f2bf(v7.x); o1.us[6] = f2bf(v7.y);
    e1.us[7] = f2bf(v7.z); o1.us[7] = f2bf(v7.w);
    size_t tb = ((size_t)(bm * 64 + kb)) << 12;      // tile base (elems)
    int c0 = (2 * h) * 1024 + r * 8;                 // g = 2h
    int c1 = c0 + 1024;                              // g = 2h+1
    *(int4*)(Ae + tb + c0) = e0.v;
    *(int4*)(Ae + tb + c1) = e1.v;
    *(int4*)(Ao + tb + c0) = o0.v;
    *(int4*)(Ao + tb + c1) = o1.v;
  } else {
    int b2 = b - 2048;
    int plane = b2 >> 10;            // 0 = Ce (even n), 1 = Co (odd n)
    int bn = (b2 & 1023) >> 6, kb = b2 & 63;
    ushort_t* T = plane ? Co : Ce;
    size_t tb = ((size_t)(bn * 64 + kb)) << 12;
    const float s = 3.14159265358979f / 8192.0f;     // pi/(2N)
#pragma unroll
    for (int half = 0; half < 2; ++half) {
      int cc = t + half * 256;       // chunk index within tile [0,512)
      int g = cc >> 7, r = cc & 127;
      int p = bn * 128 + r;
      int tp = 2 * p + 1;
      int ni = kb * 32 + g * 8;
      int n0 = 2 * ni + plane;       // entries n0, n0+2, ..., n0+14
      // Chebyshev: c_j = cos(n_j*tp*pi/8192); step angle d = 2*tp*pi/8192.
      float c0 = __cosf(s * (float)((n0 * tp) & 16383));
      float c1 = __cosf(s * (float)(((n0 + 2) * tp) & 16383));
      float T2 = 2.0f * __cosf(s * (float)(2 * tp));   // 2*tp < 8192, no mod
      union { ushort_t us[8]; int4 v; } pk;
      pk.us[0] = f2bf(2.0f * c0);
      pk.us[1] = f2bf(2.0f * c1);
#pragma unroll
      for (int jj = 2; jj < 8; ++jj) {
        float c2 = __builtin_fmaf(T2, c1, -c0);
        pk.us[jj] = f2bf(2.0f * c2);
        c0 = c1; c1 = c2;
      }
      if (plane == 0 && ni == 0) pk.us[0] = f2bf(1.0f);  // c(0,p) = 1
      *(int4*)(T + tb + cc * 8) = pk.v;
    }
  }
}

// Fused dual GEMM + butterfly. Block 128m x 128p, BK=32, 4 waves 2x2,
// wave tile 64x64 per GEMM, 32x32x16 MFMA: frags 2x2 per branch, dual acc
// E/O = 2 x 2x2 x floatx16 = 128 acc regs (same budget as R9's 16x16 form,
// half the MFMA instructions, +15% measured pipe ceiling).
// LDS: S[32768] = 2 bufs x {AsE,AsO,BsE,BsO} x 4096. Counted-vmcnt depth-2
// schedule (R9, best-measured): STAGE = 8 GLDS/wave; main-loop wait
// vmcnt(8), never 0.
// Fragment read (32x32x16): lane wants (row = base + (lane&31),
// k-chunk g = 2*kk + (lane>>5)) -> elem off g*1024 + row*8: lanes 0-31 read
// 512B contiguous, lanes 32-63 the next 512B: conflict-free.
__global__ __launch_bounds__(256, 2) void gemm_fused(const ushort_t* __restrict__ Ae,
                                                     const ushort_t* __restrict__ Ao,
                                                     const ushort_t* __restrict__ Ce,
                                                     const ushort_t* __restrict__ Co,
                                                     float* __restrict__ out) {
  __shared__ __align__(16) ushort_t S[32768];   // 64 KB

  const int tid = threadIdx.x;
  const int wid = tid >> 6;
  const int lane = tid & 63;

  // T1: XCD-bijective block swizzle. 512 blocks, 8 XCDs, chunk = 64.
  // XCD c owns swz in [c*64, c*64+64) = bm in [c*4, c*4+4), all bn ->
  // A-tiles (1MB each) reused 16x within one XCD's L2.
  const int id = blockIdx.y * gridDim.x + blockIdx.x;
  const int swz = (id & 7) * 64 + (id >> 3);
  const int bn = swz & 15;     // p-tile index (128 cols)
  const int bm = swz >> 4;     // m-tile index (128 rows)

  const int wm = (wid & 1) * 64;
  const int wn = (wid >> 1) * 64;
  const int l31 = lane & 31;
  const int lhi = lane >> 5;

  floatx16 accE[2][2] = {};
  floatx16 accO[2][2] = {};

  const int lb = wid * 512;                  // wave elem base within an issue
  const ushort_t* pAe = Ae + (((size_t)bm * NKB) << 12) + (tid << 3);
  const ushort_t* pAo = Ao + (((size_t)bm * NKB) << 12) + (tid << 3);
  const ushort_t* pBe = Ce + (((size_t)bn * NKB) << 12) + (tid << 3);
  const ushort_t* pBo = Co + (((size_t)bn * NKB) << 12) + (tid << 3);

#define GLDS(src, dst) __builtin_amdgcn_global_load_lds( \
      (const __attribute__((address_space(1))) void*)(src), \
      (__attribute__((address_space(3))) void*)(dst), 16, 0, 0)

#define STAGE(bufoff, t) do { \
    size_t so_ = ((size_t)(t)) << 12; \
    _Pragma("unroll") \
    for (int i_ = 0; i_ < 2; ++i_) { \
      GLDS(pAe + so_ + i_ * 2048, S + (bufoff) + i_ * 2048 + lb); \
      GLDS(pAo + so_ + i_ * 2048, S + (bufoff) + 4096 + i_ * 2048 + lb); \
      GLDS(pBe + so_ + i_ * 2048, S + (bufoff) + 8192 + i_ * 2048 + lb); \
      GLDS(pBo + so_ + i_ * 2048, S + (bufoff) + 12288 + i_ * 2048 + lb); \
    } } while (0)

#define COMPUTE(bufoff) do { \
    _Pragma("unroll") \
    for (int kk_ = 0; kk_ < 2; ++kk_) { \
      const int g_ = ((lhi + 2 * kk_) << 10) + (bufoff); \
      bf16x8 bE_[2], bO_[2]; \
      _Pragma("unroll") \
      for (int jn_ = 0; jn_ < 2; ++jn_) { \
        int off_ = g_ + ((wn + jn_ * 32 + l31) << 3); \
        bE_[jn_] = *(const bf16x8*)(S + 8192 + off_); \
        bO_[jn_] = *(const bf16x8*)(S + 12288 + off_); \
      } \
      __builtin_amdgcn_s_setprio(1); \
      _Pragma("unroll") \
      for (int im_ = 0; im_ < 2; ++im_) { \
        int off_ = g_ + ((wm + im_ * 32 + l31) << 3); \
        bf16x8 aE_ = *(const bf16x8*)(S + off_); \
        bf16x8 aO_ = *(const bf16x8*)(S + 4096 + off_); \
        _Pragma("unroll") \
        for (int jn_ = 0; jn_ < 2; ++jn_) { \
          accE[im_][jn_] = __builtin_amdgcn_mfma_f32_32x32x16_bf16(aE_, bE_[jn_], accE[im_][jn_], 0, 0, 0); \
          accO[im_][jn_] = __builtin_amdgcn_mfma_f32_32x32x16_bf16(aO_, bO_[jn_], accO[im_][jn_], 0, 0, 0); \
        } \
      } \
      __builtin_amdgcn_s_setprio(0); \
    } \
  } while (0)

#define WAITVM(n) do { \
    asm volatile("s_waitcnt vmcnt(" #n ")" ::: "memory"); \
    __builtin_amdgcn_sched_barrier(0); \
  } while (0)

  // Prologue: stage tiles 0 and 1 (depth-2 pipeline).
  STAGE(0, 0);
  STAGE(16384, 1);

  for (int t = 0; t < NKB - 2; ++t) {
    const int cur = (t & 1) << 14;        // 0 / 16384
    WAITVM(8);                            // tile t landed; t+1 in flight
    __builtin_amdgcn_s_barrier();
    COMPUTE(cur);
    __builtin_amdgcn_s_barrier();
    STAGE(cur, t + 2);                    // refill freed buffer
  }
  // t = NKB-2 (62): buf 0.
  WAITVM(8);
  __builtin_amdgcn_s_barrier();
  COMPUTE(0);
  // t = NKB-1 (63): buf 1 — last stage must be fully landed.
  WAITVM(0);
  __builtin_amdgcn_s_barrier();
  COMPUTE(16384);

#undef GLDS
#undef STAGE
#undef COMPUTE
#undef WAITVM

  // Epilogue butterfly. 32x32 C/D mapping [m74/m101]:
  //   col = lane&31, row = (r&3) + 8*(r>>2) + 4*(lane>>5), r in [0,16).
  // Per store: 64 lanes cover 2 rows x 32 cols = two 128B segments.
#pragma unroll
  for (int im = 0; im < 2; ++im) {
    int rb0 = bm * BM + wm + im * 32 + 4 * lhi;
#pragma unroll
    for (int jn = 0; jn < 2; ++jn) {
      int p = bn * BN + wn + jn * 32 + l31;
      float* lo = out + p;
      float* hi = out + (Nfull - 1 - p);
#pragma unroll
      for (int r = 0; r < 16; ++r) {
        int row = rb0 + (r & 3) + 8 * (r >> 2);
        float e = accE[im][jn][r];
        float o = accO[im][jn][r];
        lo[(size_t)row * Nfull] = e + o;
        hi[(size_t)row * Nfull] = e - o;
      }
    }
  }
}

extern "C" void kernel_launch(void* const* d_in, const int* in_sizes, int n_in,
                              void* d_out, int out_size, void* d_ws, size_t ws_size,
                              hipStream_t stream) {
  const float* x = (const float*)d_in[0];
  float* out = (float*)d_out;
  ushort_t* Ae = (ushort_t*)d_ws;                      // 16 MB (tiled)
  ushort_t* Ao = Ae + (size_t)8 * 1024 * 1024;         // 16 MB
  ushort_t* Ce = Ao + (size_t)8 * 1024 * 1024;         // 8 MB
  ushort_t* Co = Ce + (size_t)4 * 1024 * 1024;         // 8 MB

  prep_kernel<<<4096, 256, 0, stream>>>(x, Ae, Ao, Ce, Co);

  dim3 grid(Ph / BN, Md / BM);  // 16 x 32 = 512 blocks = 2/CU
  gemm_fused<<<grid, 256, 0, stream>>>(Ae, Ao, Ce, Co, out);
}